// Round 9
// baseline (378.463 us; speedup 1.0000x reference)
//
#include <hip/hip_runtime.h>

// B=2, T=2048, C=1024, H=16, hd=64. fp32 in/out; bf16 MFMA everywhere.
// ws (48 MB): qb bf16 8MB | kb bf16 8MB | vb bf16 8MB ([bh][t][d]) |
//             vt bf16 8MB ([bh][d][t]) | xb/yb bf16 8MB (aliased) |
//             wqkvT bf16 6MB | woutT bf16 2MB

#define T_SEQ 2048
#define C_DIM 1024
#define NH    16
#define HD    64
#define BT    4096

typedef short bf16x8 __attribute__((ext_vector_type(8)));   // 8 bf16 (4 VGPRs)
typedef float floatx4 __attribute__((ext_vector_type(4)));  // MFMA accum

static __device__ __forceinline__ unsigned short f2bf(float f) {
    union { float f; unsigned u; } v; v.f = f;
    unsigned u = v.u;
    return (unsigned short)((u + 0x7FFFu + ((u >> 16) & 1u)) >> 16);
}

// async global->LDS, 16B per lane. LDS dest must be wave-uniform base + lane*16.
static __device__ __forceinline__ void gl2lds16(const void* g, void* l) {
    __builtin_amdgcn_global_load_lds(
        (const __attribute__((address_space(1))) unsigned int*)g,
        (__attribute__((address_space(3))) unsigned int*)l, 16, 0, 0);
}

// ---------------- fused prep: x->bf16, W_qkv^T->bf16, W_out^T->bf16 --------
static __device__ __forceinline__ void transpose_body(float (*tile)[65],
                                                      const float* __restrict__ W,
                                                      unsigned short* __restrict__ Wt,
                                                      int K, int N, int bx, int by) {
    const int k0 = by << 6;
    const int n0 = bx << 6;
    const int rr = threadIdx.x >> 4;
    const int cc = (threadIdx.x & 15) << 2;
#pragma unroll
    for (int i = 0; i < 4; i++) {
        int r = rr + (i << 4);
        *(float4*)&tile[r][cc] = *(const float4*)(W + (size_t)(k0 + r) * N + n0 + cc);
    }
    __syncthreads();
#pragma unroll
    for (int i = 0; i < 4; i++) {
        int nr = rr + (i << 4);
        ushort4 o;
        o.x = f2bf(tile[cc + 0][nr]);
        o.y = f2bf(tile[cc + 1][nr]);
        o.z = f2bf(tile[cc + 2][nr]);
        o.w = f2bf(tile[cc + 3][nr]);
        *(ushort4*)(Wt + (size_t)(n0 + nr) * K + k0 + cc) = o;
    }
}

__global__ __launch_bounds__(256) void prep(const float* __restrict__ x,
                                            unsigned short* __restrict__ xb,
                                            const float* __restrict__ w_qkv,
                                            unsigned short* __restrict__ wqkvT,
                                            const float* __restrict__ w_out,
                                            unsigned short* __restrict__ woutT) {
    __shared__ float tile[64][65];
    const int bx = blockIdx.x;
    if (bx < 1024) {                       // convert x (4M floats), 4 sweeps
        int i = (bx * 256 + threadIdx.x) * 4;
        const int n = BT * C_DIM;
        const int stride = 1024 * 1024;
        for (; i < n; i += stride) {
            float4 f = *(const float4*)(x + i);
            ushort4 o;
            o.x = f2bf(f.x); o.y = f2bf(f.y); o.z = f2bf(f.z); o.w = f2bf(f.w);
            *(ushort4*)(xb + i) = o;
        }
    } else if (bx < 1024 + 768) {          // w_qkv [1024][3072] -> [3072][1024]
        int b = bx - 1024;
        transpose_body(tile, w_qkv, wqkvT, 1024, 3072, b % 48, b / 48);
    } else {                               // w_out [1024][1024] -> [1024][1024]
        int b = bx - 1024 - 768;
        transpose_body(tile, w_out, woutT, 1024, 1024, b % 16, b / 16);
    }
}

// ---------------- v [bh][t][d] -> vt [bh][d][t] (LDS tile transpose) -------
__global__ __launch_bounds__(256) void transp_v(const unsigned short* __restrict__ vb,
                                                unsigned short* __restrict__ vt) {
    __shared__ unsigned short tile[64][68];
    const int t0 = blockIdx.x << 6;
    const int bh = blockIdx.y;
    const size_t base = (size_t)bh * T_SEQ * HD;
    const int r = threadIdx.x >> 3;
    const int c = (threadIdx.x & 7) << 3;
#pragma unroll
    for (int i = 0; i < 2; i++) {
        const unsigned short* src = vb + base + (size_t)(t0 + r + (i << 5)) * HD + c;
        ushort4 u0 = *(const ushort4*)src;
        ushort4 u1 = *(const ushort4*)(src + 4);
        *(ushort4*)&tile[r + (i << 5)][c] = u0;
        *(ushort4*)&tile[r + (i << 5)][c + 4] = u1;
    }
    __syncthreads();
#pragma unroll
    for (int i = 0; i < 2; i++) {
        int s = threadIdx.x + (i << 8);
        int d = s >> 3;
        int tc = (s & 7) << 3;
        ushort4 o0, o1;
        o0.x = tile[tc + 0][d]; o0.y = tile[tc + 1][d];
        o0.z = tile[tc + 2][d]; o0.w = tile[tc + 3][d];
        o1.x = tile[tc + 4][d]; o1.y = tile[tc + 5][d];
        o1.z = tile[tc + 6][d]; o1.w = tile[tc + 7][d];
        unsigned short* dst = vt + ((size_t)bh * HD + d) * T_SEQ + t0 + tc;
        *(ushort4*)dst = o0;
        *(ushort4*)(dst + 4) = o1;
    }
}

// ---------------- m97-style bf16 MFMA GEMM core, XOR-swizzled LDS ----------
#define GEMM_CORE(A_, Bt_, K_)                                                      \
    __shared__ short As[128 * 64];                                                  \
    __shared__ short Bs[128 * 64];                                                  \
    const int tid  = threadIdx.x;                                                   \
    const int lane = tid & 63, wave = tid >> 6;                                     \
    const int ln   = lane & 15, quad = lane >> 4;                                   \
    const int wm   = wave & 1,  wn   = wave >> 1;                                   \
    const int row0 = blockIdx.y << 7;                                               \
    const int col0 = blockIdx.x << 7;                                               \
    floatx4 acc[4][4];                                                              \
    _Pragma("unroll")                                                               \
    for (int i = 0; i < 4; i++)                                                     \
        _Pragma("unroll")                                                           \
        for (int j = 0; j < 4; j++) acc[i][j] = (floatx4){0.f, 0.f, 0.f, 0.f};      \
    for (int k0 = 0; k0 < K_; k0 += 64) {                                           \
        _Pragma("unroll")                                                           \
        for (int i = 0; i < 4; i++) {                                               \
            int c = (i << 8) + tid;                                                 \
            int r = c >> 3;                                                         \
            int gsrc = (c & 7) ^ (r & 7);                                           \
            gl2lds16(A_  + (size_t)(row0 + r) * K_ + k0 + (gsrc << 3), &As[c << 3]); \
            gl2lds16(Bt_ + (size_t)(col0 + r) * K_ + k0 + (gsrc << 3), &Bs[c << 3]); \
        }                                                                           \
        __syncthreads();                                                            \
        _Pragma("unroll")                                                           \
        for (int half = 0; half < 2; half++) {                                      \
            bf16x8 af[4], bfr[4];                                                   \
            _Pragma("unroll")                                                       \
            for (int t4 = 0; t4 < 4; t4++) {                                        \
                int ra = (wm << 6) + (t4 << 4) + ln;                                \
                int rb = (wn << 6) + (t4 << 4) + ln;                                \
                int g  = (half << 2) + quad;                                        \
                af[t4]  = *(bf16x8*)&As[((ra << 3) + (g ^ (ra & 7))) << 3];         \
                bfr[t4] = *(bf16x8*)&Bs[((rb << 3) + (g ^ (rb & 7))) << 3];         \
            }                                                                       \
            _Pragma("unroll")                                                       \
            for (int mt = 0; mt < 4; mt++)                                          \
                _Pragma("unroll")                                                   \
                for (int nt = 0; nt < 4; nt++)                                      \
                    acc[mt][nt] = __builtin_amdgcn_mfma_f32_16x16x32_bf16(af[mt], bfr[nt], acc[mt][nt], 0, 0, 0); \
        }                                                                           \
        __syncthreads();                                                            \
    }

// ---------------- GEMM: qkv = X @ WqkvT^T + bias -> bf16 q/k/v (coalesced) --
__global__ __launch_bounds__(256) void gemm_qkv(const unsigned short* __restrict__ A,
                                                const unsigned short* __restrict__ Bt,
                                                const float* __restrict__ bias,
                                                unsigned short* __restrict__ qb,
                                                unsigned short* __restrict__ kb,
                                                unsigned short* __restrict__ vb) {
    GEMM_CORE(A, Bt, 1024)
#pragma unroll
    for (int mt = 0; mt < 4; mt++) {
#pragma unroll
        for (int nt = 0; nt < 4; nt++) {
            int n = col0 + (wn << 6) + (nt << 4) + ln;
            int h = n / 192, r = n % 192;
            int sel = r >> 6, d = r & 63;
            float bv = bias[n];
#pragma unroll
            for (int e = 0; e < 4; e++) {
                int m = row0 + (wm << 6) + (mt << 4) + (quad << 2) + e;
                int b = m >> 11, t = m & 2047;
                float val = acc[mt][nt][e] + bv;
                size_t idx = (((size_t)(b * NH + h)) * T_SEQ + t) * HD + d;
                if (sel == 0)
                    qb[idx] = f2bf(val * 0.125f);
                else if (sel == 1)
                    kb[idx] = f2bf(val);
                else
                    vb[idx] = f2bf(val);
            }
        }
    }
}

// ---------------- GEMM: out = Y @ WoutT^T + bias (fp32 out) ----------------
__global__ __launch_bounds__(256) void gemm_out(const unsigned short* __restrict__ A,
                                                const unsigned short* __restrict__ Bt,
                                                const float* __restrict__ bias,
                                                float* __restrict__ out) {
    GEMM_CORE(A, Bt, 1024)
    const int N = 1024;
#pragma unroll
    for (int mt = 0; mt < 4; mt++) {
#pragma unroll
        for (int nt = 0; nt < 4; nt++) {
            int n = col0 + (wn << 6) + (nt << 4) + ln;
            float bv = bias[n];
#pragma unroll
            for (int e = 0; e < 4; e++) {
                int m = row0 + (wm << 6) + (mt << 4) + (quad << 2) + e;
                out[(size_t)m * N + n] = acc[mt][nt][e] + bv;
            }
        }
    }
}

// ---------------- MFMA flash attention v5: barrier-free ----------
// Q-tile 64, K-tile 64, 4 waves, wave w owns q-rows [16w,16w+16).
// ALL MFMA operands except P load directly from global (16B/lane aligned;
// K/V tiles identical across the 4 waves -> L1-broadcast; cross-block -> L2).
// LDS holds only the wave-private P round-trip => ZERO __syncthreads().
// S^T = K·Q^T: lane holds q=ln, k=16ktl+4quad+e; softmax in-register + 2 shfl.
__global__ __launch_bounds__(256, 4) void attn(const unsigned short* __restrict__ qb,
                                               const unsigned short* __restrict__ kb,
                                               const unsigned short* __restrict__ vt,
                                               unsigned short* __restrict__ y) {
    __shared__ short P[64][72];     // P[q][k], wave-private rows [16w,16w+16)
    const int tid  = threadIdx.x;
    const int w    = tid >> 6, lane = tid & 63;
    const int ln   = lane & 15, quad = lane >> 4;
    const int qt   = 31 - (int)blockIdx.x;          // LPT: long blocks first
    const int bh   = blockIdx.y;
    const size_t base = (size_t)bh * T_SEQ * HD;
    const int q0   = qt << 6;
    const int sb   = q0 + (w << 4);                 // this wave's first q-row
    const float NEG_INF = -__builtin_inff();

    // loop-invariant Q B-frags, direct from global
    const unsigned short* qrow = qb + base + (size_t)(sb + ln) * HD;
    const bf16x8 bq0 = *(const bf16x8*)(qrow + (quad << 3));
    const bf16x8 bq1 = *(const bf16x8*)(qrow + 32 + (quad << 3));

    floatx4 o[4];
#pragma unroll
    for (int nt = 0; nt < 4; nt++) o[nt] = (floatx4){0.f, 0.f, 0.f, 0.f};
    float m_prev = NEG_INF, l_run = 0.f;            // per-lane stats for q = sb+ln

    for (int kt = 0; kt <= qt; kt++) {
        const int k0 = kt << 6;
        const bool diag  = (kt == qt);
        const int  nlive = diag ? w : 3;            // wave-uniform

        // V B-frags for this tile, hoisted so their latency overlaps softmax
        bf16x8 vf0[4], vf1[4];
#pragma unroll
        for (int nt = 0; nt < 4; nt++) {
            const unsigned short* vrow = vt + base + (size_t)((nt << 4) + ln) * T_SEQ + k0;
            vf0[nt] = *(const bf16x8*)(vrow + (quad << 3));
            vf1[nt] = *(const bf16x8*)(vrow + 32 + (quad << 3));
        }

        // S^T subtiles: K A-frags direct from global; st[ktl]: k=k0+16ktl+4quad+e, q=sb+ln
        floatx4 st[4];
#pragma unroll
        for (int ktl = 0; ktl < 4; ktl++) {
            if (ktl <= nlive) {
                const unsigned short* krow = kb + base + (size_t)(k0 + (ktl << 4) + ln) * HD;
                bf16x8 a0 = *(const bf16x8*)(krow + (quad << 3));
                bf16x8 a1 = *(const bf16x8*)(krow + 32 + (quad << 3));
                floatx4 acc = (floatx4){0.f, 0.f, 0.f, 0.f};
                acc = __builtin_amdgcn_mfma_f32_16x16x32_bf16(a0, bq0, acc, 0, 0, 0);
                acc = __builtin_amdgcn_mfma_f32_16x16x32_bf16(a1, bq1, acc, 0, 0, 0);
                st[ktl] = acc;
            }
        }
        // causal mask (diagonal tile only)
        if (diag) {
#pragma unroll
            for (int ktl = 0; ktl < 4; ktl++) {
                if (ktl <= nlive) {
#pragma unroll
                    for (int e = 0; e < 4; e++) {
                        int kg = k0 + (ktl << 4) + (quad << 2) + e;
                        if (kg > sb + ln) st[ktl][e] = NEG_INF;
                    }
                }
            }
        }

        // online softmax for q=sb+ln: in-register + 2 shfls each
        float mx = NEG_INF;
#pragma unroll
        for (int ktl = 0; ktl < 4; ktl++)
            if (ktl <= nlive) {
#pragma unroll
                for (int e = 0; e < 4; e++) mx = fmaxf(mx, st[ktl][e]);
            }
        mx = fmaxf(mx, __shfl_xor(mx, 16));
        mx = fmaxf(mx, __shfl_xor(mx, 32));
        float m_new = fmaxf(m_prev, mx);
        float alpha = __expf(m_prev - m_new);
        float psum = 0.f;
#pragma unroll
        for (int ktl = 0; ktl < 4; ktl++)
            if (ktl <= nlive) {
#pragma unroll
                for (int e = 0; e < 4; e++) {
                    float p = __expf(st[ktl][e] - m_new);
                    st[ktl][e] = p;
                    psum += p;
                }
            }
        psum += __shfl_xor(psum, 16);
        psum += __shfl_xor(psum, 32);
        l_run = l_run * alpha + psum;
        m_prev = m_new;

        // P -> LDS[q][k], b64 stores (wave-private row 16w+ln; same-wave
        // ordering to the reads below is guaranteed via lgkmcnt)
#pragma unroll
        for (int ktl = 0; ktl < 4; ktl++) {
            ushort4 pw;
            if (ktl <= nlive) {
                pw.x = f2bf(st[ktl][0]); pw.y = f2bf(st[ktl][1]);
                pw.z = f2bf(st[ktl][2]); pw.w = f2bf(st[ktl][3]);
            } else {
                pw.x = 0; pw.y = 0; pw.z = 0; pw.w = 0;
            }
            *(ushort4*)&P[(w << 4) + ln][(ktl << 4) + (quad << 2)] = pw;
        }

        // alpha to row layout (rows q=sb+4quad+e), rescale O
        float arow[4];
#pragma unroll
        for (int e = 0; e < 4; e++) arow[e] = __shfl(alpha, (quad << 2) + e);
#pragma unroll
        for (int nt = 0; nt < 4; nt++)
#pragma unroll
            for (int e = 0; e < 4; e++) o[nt][e] *= arow[e];

        // PV: A = P (LDS), B = V^T (already in regs)
        bf16x8 ap0 = *(bf16x8*)&P[(w << 4) + ln][quad << 3];
        bf16x8 ap1 = *(bf16x8*)&P[(w << 4) + ln][32 + (quad << 3)];
#pragma unroll
        for (int nt = 0; nt < 4; nt++) {
            o[nt] = __builtin_amdgcn_mfma_f32_16x16x32_bf16(ap0, vf0[nt], o[nt], 0, 0, 0);
            o[nt] = __builtin_amdgcn_mfma_f32_16x16x32_bf16(ap1, vf1[nt], o[nt], 0, 0, 0);
        }
    }

    // epilogue: y[b, t, h*64+d] bf16; l to row layout
    float linv[4];
#pragma unroll
    for (int e = 0; e < 4; e++) linv[e] = 1.0f / __shfl(l_run, (quad << 2) + e);
    const int b = bh >> 4, h = bh & 15;
#pragma unroll
    for (int e = 0; e < 4; e++) {
        int t = sb + (quad << 2) + e;
        unsigned short* yrow = y + ((size_t)b * T_SEQ + t) * C_DIM + h * HD;
#pragma unroll
        for (int nt = 0; nt < 4; nt++)
            yrow[(nt << 4) + ln] = f2bf(o[nt][e] * linv[e]);
    }
}

extern "C" void kernel_launch(void* const* d_in, const int* in_sizes, int n_in,
                              void* d_out, int out_size, void* d_ws, size_t ws_size,
                              hipStream_t stream) {
    (void)in_sizes; (void)n_in; (void)out_size; (void)ws_size;
    const float* x     = (const float*)d_in[0];
    const float* w_qkv = (const float*)d_in[1];
    const float* b_qkv = (const float*)d_in[2];
    const float* w_out = (const float*)d_in[3];
    const float* b_out = (const float*)d_in[4];
    float* out = (float*)d_out;

    char* ws = (char*)d_ws;
    unsigned short* qb    = (unsigned short*)ws;                        // 8 MB
    unsigned short* kb    = (unsigned short*)(ws + ((size_t)8  << 20)); // 8 MB
    unsigned short* vb    = (unsigned short*)(ws + ((size_t)16 << 20)); // 8 MB (row-major v)
    unsigned short* vt    = (unsigned short*)(ws + ((size_t)24 << 20)); // 8 MB (transposed v)
    unsigned short* xb    = (unsigned short*)(ws + ((size_t)32 << 20)); // 8 MB (alias yb)
    unsigned short* yb    = xb;
    unsigned short* wqkvT = (unsigned short*)(ws + ((size_t)40 << 20)); // 6 MB
    unsigned short* woutT = (unsigned short*)(ws + ((size_t)46 << 20)); // 2 MB

    prep    <<<2048, 256, 0, stream>>>(x, xb, w_qkv, wqkvT, w_out, woutT);
    gemm_qkv<<<dim3(24, 32), 256, 0, stream>>>(xb, wqkvT, b_qkv, qb, kb, vb);
    transp_v<<<dim3(32, 32), 256, 0, stream>>>(vb, vt);
    attn    <<<dim3(32, 32), 256, 0, stream>>>(qb, kb, vt, yb);
    gemm_out<<<dim3(8, 32), 256, 0, stream>>>(yb, woutT, b_out, out);
}

// Round 10
// 210.060 us; speedup vs baseline: 1.8017x; 1.8017x over previous
//
#include <hip/hip_runtime.h>

// B=2, T=2048, C=1024, H=16, hd=64. fp32 in/out; bf16 MFMA everywhere.
// ws: qb 8MB | kb 8MB | vb 8MB | vt 8MB | xb/yb 8MB (alias) | wqkvT 6MB |
//     woutT 2MB | po bf16 8MB (attn partials) | pm/pl fp32 512KB   (~56.5 MB)

#define T_SEQ 2048
#define C_DIM 1024
#define NH    16
#define HD    64
#define BT    4096

typedef short bf16x8 __attribute__((ext_vector_type(8)));   // 8 bf16 (4 VGPRs)
typedef float floatx4 __attribute__((ext_vector_type(4)));  // MFMA accum

static __device__ __forceinline__ unsigned short f2bf(float f) {
    union { float f; unsigned u; } v; v.f = f;
    unsigned u = v.u;
    return (unsigned short)((u + 0x7FFFu + ((u >> 16) & 1u)) >> 16);
}
static __device__ __forceinline__ float bf2f(unsigned short u) {
    union { unsigned u; float f; } v; v.u = ((unsigned)u) << 16; return v.f;
}

// async global->LDS, 16B per lane. LDS dest must be wave-uniform base + lane*16.
static __device__ __forceinline__ void gl2lds16(const void* g, void* l) {
    __builtin_amdgcn_global_load_lds(
        (const __attribute__((address_space(1))) unsigned int*)g,
        (__attribute__((address_space(3))) unsigned int*)l, 16, 0, 0);
}

// ---------------- fused prep: x->bf16, W_qkv^T->bf16, W_out^T->bf16 --------
static __device__ __forceinline__ void transpose_body(float (*tile)[65],
                                                      const float* __restrict__ W,
                                                      unsigned short* __restrict__ Wt,
                                                      int K, int N, int bx, int by) {
    const int k0 = by << 6;
    const int n0 = bx << 6;
    const int rr = threadIdx.x >> 4;
    const int cc = (threadIdx.x & 15) << 2;
#pragma unroll
    for (int i = 0; i < 4; i++) {
        int r = rr + (i << 4);
        *(float4*)&tile[r][cc] = *(const float4*)(W + (size_t)(k0 + r) * N + n0 + cc);
    }
    __syncthreads();
#pragma unroll
    for (int i = 0; i < 4; i++) {
        int nr = rr + (i << 4);
        ushort4 o;
        o.x = f2bf(tile[cc + 0][nr]);
        o.y = f2bf(tile[cc + 1][nr]);
        o.z = f2bf(tile[cc + 2][nr]);
        o.w = f2bf(tile[cc + 3][nr]);
        *(ushort4*)(Wt + (size_t)(n0 + nr) * K + k0 + cc) = o;
    }
}

__global__ __launch_bounds__(256) void prep(const float* __restrict__ x,
                                            unsigned short* __restrict__ xb,
                                            const float* __restrict__ w_qkv,
                                            unsigned short* __restrict__ wqkvT,
                                            const float* __restrict__ w_out,
                                            unsigned short* __restrict__ woutT) {
    __shared__ float tile[64][65];
    const int bx = blockIdx.x;
    if (bx < 1024) {                       // convert x (4M floats), 4 sweeps
        int i = (bx * 256 + threadIdx.x) * 4;
        const int n = BT * C_DIM;
        const int stride = 1024 * 1024;
        for (; i < n; i += stride) {
            float4 f = *(const float4*)(x + i);
            ushort4 o;
            o.x = f2bf(f.x); o.y = f2bf(f.y); o.z = f2bf(f.z); o.w = f2bf(f.w);
            *(ushort4*)(xb + i) = o;
        }
    } else if (bx < 1024 + 768) {          // w_qkv [1024][3072] -> [3072][1024]
        int b = bx - 1024;
        transpose_body(tile, w_qkv, wqkvT, 1024, 3072, b % 48, b / 48);
    } else {                               // w_out [1024][1024] -> [1024][1024]
        int b = bx - 1024 - 768;
        transpose_body(tile, w_out, woutT, 1024, 1024, b % 16, b / 16);
    }
}

// ---------------- v [bh][t][d] -> vt [bh][d][t] (LDS tile transpose) -------
__global__ __launch_bounds__(256) void transp_v(const unsigned short* __restrict__ vb,
                                                unsigned short* __restrict__ vt) {
    __shared__ unsigned short tile[64][68];
    const int t0 = blockIdx.x << 6;
    const int bh = blockIdx.y;
    const size_t base = (size_t)bh * T_SEQ * HD;
    const int r = threadIdx.x >> 3;
    const int c = (threadIdx.x & 7) << 3;
#pragma unroll
    for (int i = 0; i < 2; i++) {
        const unsigned short* src = vb + base + (size_t)(t0 + r + (i << 5)) * HD + c;
        ushort4 u0 = *(const ushort4*)src;
        ushort4 u1 = *(const ushort4*)(src + 4);
        *(ushort4*)&tile[r + (i << 5)][c] = u0;
        *(ushort4*)&tile[r + (i << 5)][c + 4] = u1;
    }
    __syncthreads();
#pragma unroll
    for (int i = 0; i < 2; i++) {
        int s = threadIdx.x + (i << 8);
        int d = s >> 3;
        int tc = (s & 7) << 3;
        ushort4 o0, o1;
        o0.x = tile[tc + 0][d]; o0.y = tile[tc + 1][d];
        o0.z = tile[tc + 2][d]; o0.w = tile[tc + 3][d];
        o1.x = tile[tc + 4][d]; o1.y = tile[tc + 5][d];
        o1.z = tile[tc + 6][d]; o1.w = tile[tc + 7][d];
        unsigned short* dst = vt + ((size_t)bh * HD + d) * T_SEQ + t0 + tc;
        *(ushort4*)dst = o0;
        *(ushort4*)(dst + 4) = o1;
    }
}

// ---------------- m97-style bf16 MFMA GEMM core, XOR-swizzled LDS ----------
#define GEMM_CORE(A_, Bt_, K_)                                                      \
    __shared__ short As[128 * 64];                                                  \
    __shared__ short Bs[128 * 64];                                                  \
    const int tid  = threadIdx.x;                                                   \
    const int lane = tid & 63, wave = tid >> 6;                                     \
    const int ln   = lane & 15, quad = lane >> 4;                                   \
    const int wm   = wave & 1,  wn   = wave >> 1;                                   \
    const int row0 = blockIdx.y << 7;                                               \
    const int col0 = blockIdx.x << 7;                                               \
    floatx4 acc[4][4];                                                              \
    _Pragma("unroll")                                                               \
    for (int i = 0; i < 4; i++)                                                     \
        _Pragma("unroll")                                                           \
        for (int j = 0; j < 4; j++) acc[i][j] = (floatx4){0.f, 0.f, 0.f, 0.f};      \
    for (int k0 = 0; k0 < K_; k0 += 64) {                                           \
        _Pragma("unroll")                                                           \
        for (int i = 0; i < 4; i++) {                                               \
            int c = (i << 8) + tid;                                                 \
            int r = c >> 3;                                                         \
            int gsrc = (c & 7) ^ (r & 7);                                           \
            gl2lds16(A_  + (size_t)(row0 + r) * K_ + k0 + (gsrc << 3), &As[c << 3]); \
            gl2lds16(Bt_ + (size_t)(col0 + r) * K_ + k0 + (gsrc << 3), &Bs[c << 3]); \
        }                                                                           \
        __syncthreads();                                                            \
        _Pragma("unroll")                                                           \
        for (int half = 0; half < 2; half++) {                                      \
            bf16x8 af[4], bfr[4];                                                   \
            _Pragma("unroll")                                                       \
            for (int t4 = 0; t4 < 4; t4++) {                                        \
                int ra = (wm << 6) + (t4 << 4) + ln;                                \
                int rb = (wn << 6) + (t4 << 4) + ln;                                \
                int g  = (half << 2) + quad;                                        \
                af[t4]  = *(bf16x8*)&As[((ra << 3) + (g ^ (ra & 7))) << 3];         \
                bfr[t4] = *(bf16x8*)&Bs[((rb << 3) + (g ^ (rb & 7))) << 3];         \
            }                                                                       \
            _Pragma("unroll")                                                       \
            for (int mt = 0; mt < 4; mt++)                                          \
                _Pragma("unroll")                                                   \
                for (int nt = 0; nt < 4; nt++)                                      \
                    acc[mt][nt] = __builtin_amdgcn_mfma_f32_16x16x32_bf16(af[mt], bfr[nt], acc[mt][nt], 0, 0, 0); \
        }                                                                           \
        __syncthreads();                                                            \
    }

// ---------------- GEMM: qkv = X @ WqkvT^T + bias -> bf16 q/k/v (coalesced) --
__global__ __launch_bounds__(256) void gemm_qkv(const unsigned short* __restrict__ A,
                                                const unsigned short* __restrict__ Bt,
                                                const float* __restrict__ bias,
                                                unsigned short* __restrict__ qb,
                                                unsigned short* __restrict__ kb,
                                                unsigned short* __restrict__ vb) {
    GEMM_CORE(A, Bt, 1024)
#pragma unroll
    for (int mt = 0; mt < 4; mt++) {
#pragma unroll
        for (int nt = 0; nt < 4; nt++) {
            int n = col0 + (wn << 6) + (nt << 4) + ln;
            int h = n / 192, r = n % 192;
            int sel = r >> 6, d = r & 63;
            float bv = bias[n];
#pragma unroll
            for (int e = 0; e < 4; e++) {
                int m = row0 + (wm << 6) + (mt << 4) + (quad << 2) + e;
                int b = m >> 11, t = m & 2047;
                float val = acc[mt][nt][e] + bv;
                size_t idx = (((size_t)(b * NH + h)) * T_SEQ + t) * HD + d;
                if (sel == 0)
                    qb[idx] = f2bf(val * 0.125f);
                else if (sel == 1)
                    kb[idx] = f2bf(val);
                else
                    vb[idx] = f2bf(val);
            }
        }
    }
}

// ---------------- GEMM: out = Y @ WoutT^T + bias, 128x64 tile (512 blocks) --
__global__ __launch_bounds__(256) void gemm_out(const unsigned short* __restrict__ A,
                                                const unsigned short* __restrict__ Bt,
                                                const float* __restrict__ bias,
                                                float* __restrict__ out) {
    const int K = 1024, N = 1024;
    __shared__ short As[128 * 64];
    __shared__ short Bs[64 * 64];
    const int tid  = threadIdx.x;
    const int lane = tid & 63, wave = tid >> 6;
    const int ln   = lane & 15, quad = lane >> 4;
    const int wm   = wave & 1,  wn   = wave >> 1;
    const int row0 = blockIdx.y << 7;
    const int col0 = blockIdx.x << 6;
    floatx4 acc[4][2];
#pragma unroll
    for (int i = 0; i < 4; i++)
#pragma unroll
        for (int j = 0; j < 2; j++) acc[i][j] = (floatx4){0.f, 0.f, 0.f, 0.f};
    for (int k0 = 0; k0 < K; k0 += 64) {
#pragma unroll
        for (int i = 0; i < 4; i++) {          // A: 1024 chunks
            int c = (i << 8) + tid;
            int r = c >> 3;
            int gsrc = (c & 7) ^ (r & 7);
            gl2lds16(A + (size_t)(row0 + r) * K + k0 + (gsrc << 3), &As[c << 3]);
        }
#pragma unroll
        for (int i = 0; i < 2; i++) {          // B: 512 chunks
            int c = (i << 8) + tid;
            int r = c >> 3;
            int gsrc = (c & 7) ^ (r & 7);
            gl2lds16(Bt + (size_t)(col0 + r) * K + k0 + (gsrc << 3), &Bs[c << 3]);
        }
        __syncthreads();
#pragma unroll
        for (int half = 0; half < 2; half++) {
            bf16x8 af[4], bfr[2];
#pragma unroll
            for (int t4 = 0; t4 < 4; t4++) {
                int ra = (wm << 6) + (t4 << 4) + ln;
                int g  = (half << 2) + quad;
                af[t4] = *(bf16x8*)&As[((ra << 3) + (g ^ (ra & 7))) << 3];
            }
#pragma unroll
            for (int t2 = 0; t2 < 2; t2++) {
                int rb = (wn << 5) + (t2 << 4) + ln;
                int g  = (half << 2) + quad;
                bfr[t2] = *(bf16x8*)&Bs[((rb << 3) + (g ^ (rb & 7))) << 3];
            }
#pragma unroll
            for (int mt = 0; mt < 4; mt++)
#pragma unroll
                for (int nt = 0; nt < 2; nt++)
                    acc[mt][nt] = __builtin_amdgcn_mfma_f32_16x16x32_bf16(af[mt], bfr[nt], acc[mt][nt], 0, 0, 0);
        }
        __syncthreads();
    }
#pragma unroll
    for (int mt = 0; mt < 4; mt++) {
#pragma unroll
        for (int nt = 0; nt < 2; nt++) {
            int n = col0 + (wn << 5) + (nt << 4) + ln;
            float bv = bias[n];
#pragma unroll
            for (int e = 0; e < 4; e++) {
                int m = row0 + (wm << 6) + (mt << 4) + (quad << 2) + e;
                out[(size_t)m * N + n] = acc[mt][nt][e] + bv;
            }
        }
    }
}

// ---------------- MFMA flash attention pass1: kt-split (round-8 core) ------
// bx<16:  qt=31-bx,      chunk0 = kt 0..15  (no diag)  -> partials
// bx<32:  qt=31-(bx-16), chunk1 = kt 16..qt (diag)     -> partials
// bx>=32: qt=15-(bx-32), full   = kt 0..qt  (diag)     -> final y
__global__ __launch_bounds__(256, 4) void attn_p1(const unsigned short* __restrict__ qb,
                                                  const unsigned short* __restrict__ kb,
                                                  const unsigned short* __restrict__ vt,
                                                  unsigned short* __restrict__ y,
                                                  unsigned short* __restrict__ po,
                                                  float* __restrict__ pm,
                                                  float* __restrict__ pl) {
    __shared__ short Ks[64][72];
    __shared__ short Vs[64][72];
    __shared__ short QP[64][72];
    const int tid  = threadIdx.x;
    const int w    = tid >> 6, lane = tid & 63;
    const int ln   = lane & 15, quad = lane >> 4;
    const int bx   = blockIdx.x;
    int qt, cidx, kt_lo; bool fin;
    if (bx < 16)      { qt = 31 - bx;        cidx = 0; kt_lo = 0;  fin = false; }
    else if (bx < 32) { qt = 31 - (bx - 16); cidx = 1; kt_lo = 16; fin = false; }
    else              { qt = 15 - (bx - 32); cidx = 0; kt_lo = 0;  fin = true;  }
    const int kt_hi = (!fin && cidx == 0) ? 15 : qt;
    const int bh   = blockIdx.y;
    const size_t base = (size_t)bh * T_SEQ * HD;
    const int q0   = qt << 6;
    const int sb   = q0 + (w << 4);
    const float NEG_INF = -__builtin_inff();

    const int sr = tid >> 3;
    const int sc = (tid & 7) << 3;

    // stage Q -> QP, prefetch K/V tile kt_lo into regs
    bf16x8 qtmp[2], kreg[2], vreg[2];
    const int kk0 = kt_lo << 6;
#pragma unroll
    for (int i = 0; i < 2; i++) {
        qtmp[i] = *(const bf16x8*)(qb + base + (size_t)(q0 + sr + (i << 5)) * HD + sc);
        kreg[i] = *(const bf16x8*)(kb + base + (size_t)(kk0 + sr + (i << 5)) * HD + sc);
        vreg[i] = *(const bf16x8*)(vt + base + (size_t)(sr + (i << 5)) * T_SEQ + kk0 + sc);
    }
#pragma unroll
    for (int i = 0; i < 2; i++) *(bf16x8*)&QP[sr + (i << 5)][sc] = qtmp[i];
    __syncthreads();

    bf16x8 bq0 = *(bf16x8*)&QP[(w << 4) + ln][quad << 3];
    bf16x8 bq1 = *(bf16x8*)&QP[(w << 4) + ln][32 + (quad << 3)];

    floatx4 o[4];
#pragma unroll
    for (int nt = 0; nt < 4; nt++) o[nt] = (floatx4){0.f, 0.f, 0.f, 0.f};
    float m_prev = NEG_INF, l_run = 0.f;

    for (int kt = kt_lo; kt <= kt_hi; kt++) {
        const int k0 = kt << 6;
        __syncthreads();
#pragma unroll
        for (int i = 0; i < 2; i++) {
            *(bf16x8*)&Ks[sr + (i << 5)][sc] = kreg[i];
            *(bf16x8*)&Vs[sr + (i << 5)][sc] = vreg[i];
        }
        __syncthreads();
        if (kt < kt_hi) {
            const int kn = k0 + 64;
#pragma unroll
            for (int i = 0; i < 2; i++) {
                kreg[i] = *(const bf16x8*)(kb + base + (size_t)(kn + sr + (i << 5)) * HD + sc);
                vreg[i] = *(const bf16x8*)(vt + base + (size_t)(sr + (i << 5)) * T_SEQ + kn + sc);
            }
        }

        const bool diag  = (kt == qt);
        const int  nlive = diag ? w : 3;

        floatx4 st[4];
#pragma unroll
        for (int ktl = 0; ktl < 4; ktl++) {
            if (ktl <= nlive) {
                bf16x8 a0 = *(bf16x8*)&Ks[(ktl << 4) + ln][quad << 3];
                bf16x8 a1 = *(bf16x8*)&Ks[(ktl << 4) + ln][32 + (quad << 3)];
                floatx4 acc = (floatx4){0.f, 0.f, 0.f, 0.f};
                acc = __builtin_amdgcn_mfma_f32_16x16x32_bf16(a0, bq0, acc, 0, 0, 0);
                acc = __builtin_amdgcn_mfma_f32_16x16x32_bf16(a1, bq1, acc, 0, 0, 0);
                st[ktl] = acc;
            }
        }
        if (diag) {
#pragma unroll
            for (int ktl = 0; ktl < 4; ktl++) {
                if (ktl <= nlive) {
#pragma unroll
                    for (int e = 0; e < 4; e++) {
                        int kg = k0 + (ktl << 4) + (quad << 2) + e;
                        if (kg > sb + ln) st[ktl][e] = NEG_INF;
                    }
                }
            }
        }

        float mx = NEG_INF;
#pragma unroll
        for (int ktl = 0; ktl < 4; ktl++)
            if (ktl <= nlive) {
#pragma unroll
                for (int e = 0; e < 4; e++) mx = fmaxf(mx, st[ktl][e]);
            }
        mx = fmaxf(mx, __shfl_xor(mx, 16));
        mx = fmaxf(mx, __shfl_xor(mx, 32));
        float m_new = fmaxf(m_prev, mx);
        float alpha = __expf(m_prev - m_new);
        float psum = 0.f;
#pragma unroll
        for (int ktl = 0; ktl < 4; ktl++)
            if (ktl <= nlive) {
#pragma unroll
                for (int e = 0; e < 4; e++) {
                    float p = __expf(st[ktl][e] - m_new);
                    st[ktl][e] = p;
                    psum += p;
                }
            }
        psum += __shfl_xor(psum, 16);
        psum += __shfl_xor(psum, 32);
        l_run = l_run * alpha + psum;
        m_prev = m_new;

#pragma unroll
        for (int ktl = 0; ktl < 4; ktl++) {
            ushort4 pw;
            if (ktl <= nlive) {
                pw.x = f2bf(st[ktl][0]); pw.y = f2bf(st[ktl][1]);
                pw.z = f2bf(st[ktl][2]); pw.w = f2bf(st[ktl][3]);
            } else {
                pw.x = 0; pw.y = 0; pw.z = 0; pw.w = 0;
            }
            *(ushort4*)&QP[(w << 4) + ln][(ktl << 4) + (quad << 2)] = pw;
        }

        float arow[4];
#pragma unroll
        for (int e = 0; e < 4; e++) arow[e] = __shfl(alpha, (quad << 2) + e);
#pragma unroll
        for (int nt = 0; nt < 4; nt++)
#pragma unroll
            for (int e = 0; e < 4; e++) o[nt][e] *= arow[e];

        bf16x8 ap0 = *(bf16x8*)&QP[(w << 4) + ln][quad << 3];
        bf16x8 ap1 = *(bf16x8*)&QP[(w << 4) + ln][32 + (quad << 3)];
#pragma unroll
        for (int nt = 0; nt < 4; nt++) {
            bf16x8 v0 = *(bf16x8*)&Vs[(nt << 4) + ln][quad << 3];
            bf16x8 v1 = *(bf16x8*)&Vs[(nt << 4) + ln][32 + (quad << 3)];
            o[nt] = __builtin_amdgcn_mfma_f32_16x16x32_bf16(ap0, v0, o[nt], 0, 0, 0);
            o[nt] = __builtin_amdgcn_mfma_f32_16x16x32_bf16(ap1, v1, o[nt], 0, 0, 0);
        }
    }

    if (fin) {
        // final epilogue: y[b, t, h*64+d] bf16
        float linv[4];
#pragma unroll
        for (int e = 0; e < 4; e++) linv[e] = 1.0f / __shfl(l_run, (quad << 2) + e);
        const int b = bh >> 4, h = bh & 15;
#pragma unroll
        for (int e = 0; e < 4; e++) {
            int t = sb + (quad << 2) + e;
            unsigned short* yrow = y + ((size_t)b * T_SEQ + t) * C_DIM + h * HD;
#pragma unroll
            for (int nt = 0; nt < 4; nt++)
                yrow[(nt << 4) + ln] = f2bf(o[nt][e] * linv[e]);
        }
    } else {
        // partial epilogue: unnormalized o (bf16) + m,l (fp32)
        const int slot = (((bh << 4) + (qt - 16)) << 1) + cidx;    // 0..1023
        if (quad == 0) {
            pm[(slot << 6) + (w << 4) + ln] = m_prev;
            pl[(slot << 6) + (w << 4) + ln] = l_run;
        }
#pragma unroll
        for (int e = 0; e < 4; e++) {
            int q = (w << 4) + (quad << 2) + e;
            unsigned short* porow = po + (((size_t)slot << 6) + q) * HD;
#pragma unroll
            for (int nt = 0; nt < 4; nt++)
                porow[(nt << 4) + ln] = f2bf(o[nt][e]);
        }
    }
}

// ---------------- attn pass2: merge the two kt-chunks for qt>=16 ----------
__global__ __launch_bounds__(256) void attn_p2(const unsigned short* __restrict__ po,
                                               const float* __restrict__ pm,
                                               const float* __restrict__ pl,
                                               unsigned short* __restrict__ y) {
    const int qt = 16 + blockIdx.x;
    const int bh = blockIdx.y;
    const int slot0 = ((bh << 4) + (qt - 16)) << 1;
    const int tid = threadIdx.x;
    const int q  = tid >> 2;
    const int d0 = (tid & 3) << 4;
    float m0 = pm[(slot0 << 6) + q], m1 = pm[((slot0 + 1) << 6) + q];
    float l0 = pl[(slot0 << 6) + q], l1 = pl[((slot0 + 1) << 6) + q];
    float m  = fmaxf(m0, m1);
    float a0 = __expf(m0 - m), a1 = __expf(m1 - m);
    float inv = 1.0f / (l0 * a0 + l1 * a1);
    a0 *= inv; a1 *= inv;
    const unsigned short* r0 = po + (((size_t)slot0 << 6) + q) * HD + d0;
    const unsigned short* r1 = po + (((size_t)(slot0 + 1) << 6) + q) * HD + d0;
    const int b = bh >> 4, h = bh & 15;
    const int t = (qt << 6) + q;
    unsigned short* yrow = y + ((size_t)b * T_SEQ + t) * C_DIM + h * HD + d0;
#pragma unroll
    for (int i = 0; i < 4; i++) {
        ushort4 u0 = *(const ushort4*)(r0 + (i << 2));
        ushort4 u1 = *(const ushort4*)(r1 + (i << 2));
        ushort4 ow;
        ow.x = f2bf(bf2f(u0.x) * a0 + bf2f(u1.x) * a1);
        ow.y = f2bf(bf2f(u0.y) * a0 + bf2f(u1.y) * a1);
        ow.z = f2bf(bf2f(u0.z) * a0 + bf2f(u1.z) * a1);
        ow.w = f2bf(bf2f(u0.w) * a0 + bf2f(u1.w) * a1);
        *(ushort4*)(yrow + (i << 2)) = ow;
    }
}

extern "C" void kernel_launch(void* const* d_in, const int* in_sizes, int n_in,
                              void* d_out, int out_size, void* d_ws, size_t ws_size,
                              hipStream_t stream) {
    (void)in_sizes; (void)n_in; (void)out_size; (void)ws_size;
    const float* x     = (const float*)d_in[0];
    const float* w_qkv = (const float*)d_in[1];
    const float* b_qkv = (const float*)d_in[2];
    const float* w_out = (const float*)d_in[3];
    const float* b_out = (const float*)d_in[4];
    float* out = (float*)d_out;

    char* ws = (char*)d_ws;
    unsigned short* qb    = (unsigned short*)ws;                        // 8 MB
    unsigned short* kb    = (unsigned short*)(ws + ((size_t)8  << 20)); // 8 MB
    unsigned short* vb    = (unsigned short*)(ws + ((size_t)16 << 20)); // 8 MB
    unsigned short* vt    = (unsigned short*)(ws + ((size_t)24 << 20)); // 8 MB
    unsigned short* xb    = (unsigned short*)(ws + ((size_t)32 << 20)); // 8 MB (alias yb)
    unsigned short* yb    = xb;
    unsigned short* wqkvT = (unsigned short*)(ws + ((size_t)40 << 20)); // 6 MB
    unsigned short* woutT = (unsigned short*)(ws + ((size_t)46 << 20)); // 2 MB
    unsigned short* po    = (unsigned short*)(ws + ((size_t)48 << 20)); // 8 MB
    float*          pm    = (float*)(ws + ((size_t)56 << 20));          // 256 KB
    float*          pl    = (float*)(ws + ((size_t)56 << 20) + (256 << 10)); // 256 KB

    prep    <<<2048, 256, 0, stream>>>(x, xb, w_qkv, wqkvT, w_out, woutT);
    gemm_qkv<<<dim3(24, 32), 256, 0, stream>>>(xb, wqkvT, b_qkv, qb, kb, vb);
    transp_v<<<dim3(32, 32), 256, 0, stream>>>(vb, vt);
    attn_p1 <<<dim3(48, 32), 256, 0, stream>>>(qb, kb, vt, yb, po, pm, pl);
    attn_p2 <<<dim3(16, 32), 256, 0, stream>>>(po, pm, pl, yb);
    gemm_out<<<dim3(16, 32), 256, 0, stream>>>(yb, woutT, b_out, out);
}